// Round 1
// baseline (3664.375 us; speedup 1.0000x reference)
//
#include <hip/hip_runtime.h>
#include <math.h>

#define NN 128
#define EE 4096
#define DDIM 130
#define HH 64
#define DH 8320

// ws layout (float offsets)
#define F_AMIN 0
#define F_AMAX 1
#define F_EPACK 8       // float2[4096] (src bits, a) sorted by dst
#define F_OFF 8200      // int[129] dst segment offsets
#define F_AGG1 8336     // float[128*64]
#define F_XB1 16528     // float[128*64]
#define F_ROOTX1 24720  // float[128*64]
#define F_H1 32912      // float[128*64]
#define F_XB2 41104     // float[128*64]
#define F_ROOTX2 49296  // float[128*64]
#define F_H2 57488      // float[128*64]
#define F_G2 65680      // float[128*64*64]

__global__ void k_prep(const int* __restrict__ ei, const float* __restrict__ ea,
                       float* __restrict__ ws) {
  __shared__ int cnt[NN];
  __shared__ int offs[NN + 1];
  __shared__ int cur[NN];
  __shared__ float red[256];
  int t = threadIdx.x;
  if (t < NN) cnt[t] = 0;
  __syncthreads();
  for (int e = t; e < EE; e += 256) atomicAdd(&cnt[ei[EE + e]], 1);
  __syncthreads();
  if (t == 0) {
    int run = 0;
    for (int d = 0; d < NN; ++d) { offs[d] = run; run += cnt[d]; }
    offs[NN] = run;
  }
  __syncthreads();
  if (t < NN) cur[t] = offs[t];
  __syncthreads();
  float2* ep = (float2*)(ws + F_EPACK);
  for (int e = t; e < EE; e += 256) {
    int d = ei[EE + e];
    int p = atomicAdd(&cur[d], 1);
    float2 pr;
    pr.x = __int_as_float(ei[e]);  // src
    pr.y = ea[e];
    ep[p] = pr;
  }
  // min/max over edge_attr (for exact dead-row elimination)
  float mn = 1e30f, mx = -1e30f;
  for (int e = t; e < EE; e += 256) {
    float a = ea[e];
    mn = fminf(mn, a);
    mx = fmaxf(mx, a);
  }
  red[t] = mn; __syncthreads();
  for (int s = 128; s > 0; s >>= 1) { if (t < s) red[t] = fminf(red[t], red[t + s]); __syncthreads(); }
  if (t == 0) ws[F_AMIN] = red[0];
  __syncthreads();
  red[t] = mx; __syncthreads();
  for (int s = 128; s > 0; s >>= 1) { if (t < s) red[t] = fmaxf(red[t], red[t + s]); __syncthreads(); }
  if (t == 0) ws[F_AMAX] = red[0];
  int* off_g = (int*)(ws + F_OFF);
  if (t <= NN) off_g[t] = offs[t];
}

__global__ void k_rootxb1(const float* __restrict__ x, const float* __restrict__ Wr1,
                          const float* __restrict__ b1b, float* __restrict__ ws) {
  int n = blockIdx.x, o = threadIdx.x;
  float s1 = 0.f, s2 = 0.f;
  for (int i = 0; i < DDIM; ++i) {
    float xv = x[n * DDIM + i];
    s1 = fmaf(xv, Wr1[i * HH + o], s1);
    s2 = fmaf(xv, b1b[i * HH + o], s2);
  }
  ws[F_ROOTX1 + n * HH + o] = s1;
  ws[F_XB1 + n * HH + o] = s2;
}

__global__ __launch_bounds__(512, 1)
void k_conv1(const float* __restrict__ x, const float* __restrict__ W1a,
             const float* __restrict__ b1a, const float* __restrict__ W1b,
             float* __restrict__ ws) {
  __shared__ float xs[DDIM * NN];   // x transposed [i][n]
  __shared__ float wch[65 * HH];    // half of one W1b row, [il][o]
  __shared__ float gj[NN * HH];     // G_j [n][o]
  int tid = threadIdx.x;
  int w = tid >> 6;   // wave 0..7
  int o = tid & 63;   // lane = output o
  for (int idx = tid; idx < NN * DDIM; idx += 512) {
    int n = idx / DDIM, i = idx - n * DDIM;
    xs[i * NN + n] = x[idx];
  }
  float amin = ws[F_AMIN], amax = ws[F_AMAX];
  const float2* ep = (const float2*)(ws + F_EPACK);
  const int* off = (const int*)(ws + F_OFF);
  float agg[16];
#pragma unroll
  for (int k = 0; k < 16; ++k) agg[k] = 0.f;
  __syncthreads();
  int j0 = blockIdx.x * 32;
  for (int jj = 0; jj < 32; ++jj) {
    int j = j0 + jj;
    float u = W1a[j], v = b1a[j];
    // exact skip: relu(a*u+v)==0 for every edge (block-uniform branch)
    if (fmaxf(fmaf(u, amin, v), fmaf(u, amax, v)) <= 0.f) continue;
    float acc[16];
#pragma unroll
    for (int k = 0; k < 16; ++k) acc[k] = 0.f;
#pragma unroll
    for (int c = 0; c < 2; ++c) {
      __syncthreads();  // protect wch (and, at c==0, gj from prior edge phase)
      const float* wsrc = W1b + (size_t)j * DH + c * 4160;
      for (int k2 = tid; k2 < 4160; k2 += 512) wch[k2] = wsrc[k2];
      __syncthreads();
      for (int il = 0; il < 65; ++il) {
        float wv = wch[il * HH + o];
        int i = c * 65 + il;
        const float4* xp = (const float4*)&xs[i * NN + w * 16];
        float4 x0 = xp[0], x1 = xp[1], x2 = xp[2], x3 = xp[3];
        acc[0]  = fmaf(x0.x, wv, acc[0]);
        acc[1]  = fmaf(x0.y, wv, acc[1]);
        acc[2]  = fmaf(x0.z, wv, acc[2]);
        acc[3]  = fmaf(x0.w, wv, acc[3]);
        acc[4]  = fmaf(x1.x, wv, acc[4]);
        acc[5]  = fmaf(x1.y, wv, acc[5]);
        acc[6]  = fmaf(x1.z, wv, acc[6]);
        acc[7]  = fmaf(x1.w, wv, acc[7]);
        acc[8]  = fmaf(x2.x, wv, acc[8]);
        acc[9]  = fmaf(x2.y, wv, acc[9]);
        acc[10] = fmaf(x2.z, wv, acc[10]);
        acc[11] = fmaf(x2.w, wv, acc[11]);
        acc[12] = fmaf(x3.x, wv, acc[12]);
        acc[13] = fmaf(x3.y, wv, acc[13]);
        acc[14] = fmaf(x3.z, wv, acc[14]);
        acc[15] = fmaf(x3.w, wv, acc[15]);
      }
    }
    __syncthreads();
#pragma unroll
    for (int nn = 0; nn < 16; ++nn) gj[(w * 16 + nn) * HH + o] = acc[nn];
    __syncthreads();
#pragma unroll
    for (int dd = 0; dd < 16; ++dd) {
      int d = dd * 8 + w;
      int e0 = off[d], e1 = off[d + 1];
      float s = 0.f;
      for (int e = e0; e < e1; ++e) {
        float2 pr = ep[e];
        int src = __float_as_int(pr.x);
        float h = fmaxf(fmaf(pr.y, u, v), 0.f);
        s = fmaf(h, gj[src * HH + o], s);
      }
      agg[dd] += s;
    }
  }
  float* agg1 = ws + F_AGG1;
#pragma unroll
  for (int dd = 0; dd < 16; ++dd) {
    int d = dd * 8 + w;
    atomicAdd(&agg1[d * HH + o], agg[dd]);
  }
}

__global__ void k_combine1(const float* __restrict__ bc1, float* __restrict__ ws) {
  int d = blockIdx.x, o = threadIdx.x;
  const int* off = (const int*)(ws + F_OFF);
  const float2* ep = (const float2*)(ws + F_EPACK);
  int e0 = off[d], e1 = off[d + 1];
  float xbs = 0.f;
  for (int e = e0; e < e1; ++e) {
    int src = __float_as_int(ep[e].x);
    xbs += ws[F_XB1 + src * HH + o];
  }
  int c0 = e1 - e0;
  float cntd = (float)(c0 > 0 ? c0 : 1);
  float val = (ws[F_AGG1 + d * HH + o] + xbs) / cntd + ws[F_ROOTX1 + d * HH + o] + bc1[o];
  ws[F_H1 + d * HH + o] = fmaxf(val, 0.f);
}

__global__ void k_G2(const float* __restrict__ W2b, float* __restrict__ ws) {
  __shared__ float hrow[HH];
  int n = blockIdx.x, t = threadIdx.x;
  if (t < HH) hrow[t] = ws[F_H1 + n * HH + t];
  __syncthreads();
  for (int idx = t; idx < HH * HH; idx += 256) {
    int j = idx >> 6, oo = idx & 63;
    float acc = 0.f;
    for (int i = 0; i < HH; ++i) acc = fmaf(hrow[i], W2b[j * 4096 + i * HH + oo], acc);
    ws[F_G2 + n * 4096 + idx] = acc;
  }
}

__global__ void k_small2(const float* __restrict__ b2b, const float* __restrict__ Wr2,
                         float* __restrict__ ws) {
  int n = blockIdx.x, o = threadIdx.x;
  float s1 = 0.f, s2 = 0.f;
  for (int i = 0; i < HH; ++i) {
    float hv = ws[F_H1 + n * HH + i];
    s1 = fmaf(hv, Wr2[i * HH + o], s1);
    s2 = fmaf(hv, b2b[i * HH + o], s2);
  }
  ws[F_ROOTX2 + n * HH + o] = s1;
  ws[F_XB2 + n * HH + o] = s2;
}

__global__ void k_edge2(const float* __restrict__ W2a, const float* __restrict__ b2a,
                        const float* __restrict__ bc2, float* __restrict__ ws) {
  __shared__ float gsh[HH];
  int d = blockIdx.x, o = threadIdx.x;
  const int* off = (const int*)(ws + F_OFF);
  const float2* ep = (const float2*)(ws + F_EPACK);
  float w2 = W2a[o], bb = b2a[o];
  int e0 = off[d], e1 = off[d + 1];
  float acc = 0.f, xbs = 0.f;
  for (int e = e0; e < e1; ++e) {
    float2 pr = ep[e];
    int src = __float_as_int(pr.x);
    __syncthreads();
    gsh[o] = fmaxf(fmaf(pr.y, w2, bb), 0.f);
    __syncthreads();
    float s = 0.f;
    const float* g2row = ws + F_G2 + src * 4096;
#pragma unroll 8
    for (int jq = 0; jq < HH; ++jq) s = fmaf(gsh[jq], g2row[jq * HH + o], s);
    acc += s;
    xbs += ws[F_XB2 + src * HH + o];
  }
  int c0 = e1 - e0;
  float cntd = (float)(c0 > 0 ? c0 : 1);
  float val = (acc + xbs) / cntd + ws[F_ROOTX2 + d * HH + o] + bc2[o];
  ws[F_H2 + d * HH + o] = fmaxf(val, 0.f);
}

__global__ void k_out(const float* __restrict__ Wout, const float* __restrict__ bout,
                      const int* __restrict__ adj, const float* __restrict__ npk,
                      const float* __restrict__ ws, float* __restrict__ out) {
  __shared__ float h2row[HH];
  __shared__ float red[128];
  int d = blockIdx.x, m = threadIdx.x;
  if (m < HH) h2row[m] = ws[F_H2 + d * HH + m];
  __syncthreads();
  float lg = bout[m];
  for (int oo = 0; oo < HH; ++oo) lg = fmaf(h2row[oo], Wout[oo * NN + m], lg);
  bool on = adj[d * NN + m] != 0;
  red[m] = on ? lg : -1e30f;
  __syncthreads();
  for (int s2 = 64; s2 > 0; s2 >>= 1) { if (m < s2) red[m] = fmaxf(red[m], red[m + s2]); __syncthreads(); }
  float mx = red[0];
  __syncthreads();
  float p = on ? expf(lg - mx) : 0.f;
  red[m] = p;
  __syncthreads();
  for (int s2 = 64; s2 > 0; s2 >>= 1) { if (m < s2) red[m] += red[m + s2]; __syncthreads(); }
  float prob = p / red[0];
  float np = npk[d];
  out[d * NN + m] = (np == -1.0f) ? ((m == d) ? 1.f : 0.f) : prob;
}

extern "C" void kernel_launch(void* const* d_in, const int* in_sizes, int n_in,
                              void* d_out, int out_size, void* d_ws, size_t ws_size,
                              hipStream_t stream) {
  const float* x   = (const float*)d_in[0];
  const int*   ei  = (const int*)d_in[1];
  const float* ea  = (const float*)d_in[2];
  const int*   adj = (const int*)d_in[3];
  const float* npk = (const float*)d_in[4];
  const float* W1a = (const float*)d_in[5];
  const float* b1a = (const float*)d_in[6];
  const float* W1b = (const float*)d_in[7];
  const float* b1b = (const float*)d_in[8];
  const float* Wr1 = (const float*)d_in[9];
  const float* bc1 = (const float*)d_in[10];
  const float* W2a = (const float*)d_in[11];
  const float* b2a = (const float*)d_in[12];
  const float* W2b = (const float*)d_in[13];
  const float* b2b = (const float*)d_in[14];
  const float* Wr2 = (const float*)d_in[15];
  const float* bc2 = (const float*)d_in[16];
  const float* Wout = (const float*)d_in[17];
  const float* bout = (const float*)d_in[18];
  float* ws = (float*)d_ws;
  float* out = (float*)d_out;

  hipMemsetAsync(ws + F_AGG1, 0, (size_t)NN * HH * sizeof(float), stream);
  k_prep<<<1, 256, 0, stream>>>(ei, ea, ws);
  k_rootxb1<<<NN, HH, 0, stream>>>(x, Wr1, b1b, ws);
  k_conv1<<<260, 512, 0, stream>>>(x, W1a, b1a, W1b, ws);
  k_combine1<<<NN, HH, 0, stream>>>(bc1, ws);
  k_G2<<<NN, 256, 0, stream>>>(W2b, ws);
  k_small2<<<NN, HH, 0, stream>>>(b2b, Wr2, ws);
  k_edge2<<<NN, HH, 0, stream>>>(W2a, b2a, bc2, ws);
  k_out<<<NN, 128, 0, stream>>>(Wout, bout, adj, npk, ws, out);
}

// Round 2
// 670.298 us; speedup vs baseline: 5.4668x; 5.4668x over previous
//
#include <hip/hip_runtime.h>
#include <math.h>

#define NN 128
#define EE 4096
#define NI1 130
#define HH 64
#define DH 8320
#define NSLOT (EE + NN)  // 4224 prefix slots (deg_d+1 per d)

typedef __attribute__((ext_vector_type(8))) short short8v;
typedef __attribute__((ext_vector_type(4))) float f32x4;

// ws float offsets
#define F_MM      0                      // amin, amax
#define F_EPACK   8                      // float2[4096] (src bits, a) sorted by (dst, a)
#define F_OFFG    8200                   // int[129]
#define F_ROOTX1  8352                   // float[128*64]
#define F_H1      16544                  // float[128*64]
#define F_H2      24736                  // float[128*64]
#define F_SLAB1   32928                  // float[256][8192]
#define F_SLAB2   (F_SLAB1 + 256*8192)   // float[65][8192]
#define F_S0      (F_SLAB2 + 65*8192)    // ushort[4224*130] each (65 floats/slot)
#define F_S1      (F_S0 + NSLOT*65)
#define F_R0      (F_S1 + NSLOT*65)
#define F_R1      (F_R0 + NSLOT*65)
#define F_T0      (F_R1 + NSLOT*65)      // ushort[4224*64] each (32 floats/slot)
#define F_T1      (F_T0 + NSLOT*32)
#define F_U0      (F_T1 + NSLOT*32)
#define F_U1      (F_U0 + NSLOT*32)

__device__ __forceinline__ ushort f2b(float f) {
  union { float f; unsigned u; } x; x.f = f;
  unsigned r = (x.u + 0x7FFFu + ((x.u >> 16) & 1u)) >> 16;
  return (ushort)r;
}
__device__ __forceinline__ float b2f(ushort h) {
  union { unsigned u; float f; } x; x.u = ((unsigned)h) << 16; return x.f;
}

// ---------- prep0: sort edges by (dst, a asc), offsets, amin/amax ----------
__global__ void k_prep0(const int* __restrict__ ei, const float* __restrict__ ea,
                        float* __restrict__ ws) {
  __shared__ int cnt[NN];
  __shared__ int base[NN + 1];
  __shared__ int cur[NN];
  __shared__ float a_l[EE];
  __shared__ int src_l[EE];
  __shared__ float red[256];
  int t = threadIdx.x;
  if (t < NN) cnt[t] = 0;
  __syncthreads();
  for (int e = t; e < EE; e += 256) atomicAdd(&cnt[ei[EE + e]], 1);
  __syncthreads();
  if (t == 0) { int run = 0; for (int d = 0; d < NN; ++d) { base[d] = run; run += cnt[d]; } base[NN] = run; }
  __syncthreads();
  if (t < NN) cur[t] = base[t];
  __syncthreads();
  for (int e = t; e < EE; e += 256) {
    int d = ei[EE + e];
    int p = atomicAdd(&cur[d], 1);
    a_l[p] = ea[e]; src_l[p] = ei[e];
  }
  __syncthreads();
  if (t < NN) {  // insertion sort each segment by a ascending
    int b0 = base[t], n = cnt[t];
    for (int a = 1; a < n; ++a) {
      float key = a_l[b0 + a]; int ks = src_l[b0 + a];
      int b2 = a - 1;
      while (b2 >= 0 && a_l[b0 + b2] > key) {
        a_l[b0 + b2 + 1] = a_l[b0 + b2]; src_l[b0 + b2 + 1] = src_l[b0 + b2]; --b2;
      }
      a_l[b0 + b2 + 1] = key; src_l[b0 + b2 + 1] = ks;
    }
  }
  __syncthreads();
  float2* ep = (float2*)(ws + F_EPACK);
  for (int e = t; e < EE; e += 256) {
    float2 pr; pr.x = __int_as_float(src_l[e]); pr.y = a_l[e];
    ep[e] = pr;
  }
  int* off_g = (int*)(ws + F_OFFG);
  if (t <= NN) off_g[t] = base[t];
  float mn = 1e30f, mx = -1e30f;
  for (int e = t; e < EE; e += 256) { mn = fminf(mn, a_l[e]); mx = fmaxf(mx, a_l[e]); }
  red[t] = mn; __syncthreads();
  for (int s = 128; s > 0; s >>= 1) { if (t < s) red[t] = fminf(red[t], red[t + s]); __syncthreads(); }
  if (t == 0) ws[F_MM] = red[0];
  __syncthreads();
  red[t] = mx; __syncthreads();
  for (int s = 128; s > 0; s >>= 1) { if (t < s) red[t] = fmaxf(red[t], red[t + s]); __syncthreads(); }
  if (t == 0) ws[F_MM + 1] = red[0];
}

// ---------- prep1: prefix/suffix sums of x[src,i] and a*x[src,i] per dst ----------
__global__ void k_prep1(const float* __restrict__ x, float* __restrict__ ws) {
  int d = blockIdx.x, i = threadIdx.x;
  const int* off = (const int*)(ws + F_OFFG);
  const float2* ep = (const float2*)(ws + F_EPACK);
  ushort* S0 = (ushort*)(ws + F_S0); ushort* S1 = (ushort*)(ws + F_S1);
  ushort* R0 = (ushort*)(ws + F_R0); ushort* R1 = (ushort*)(ws + F_R1);
  int e0 = off[d], deg = off[d + 1] - e0;
  size_t Bd = (size_t)(e0 + d);
  if (i >= NI1) return;
  float a0 = 0.f, a1 = 0.f;
  for (int k = 0; k < deg; ++k) {
    S0[(Bd + k) * NI1 + i] = f2b(a0); S1[(Bd + k) * NI1 + i] = f2b(a1);
    float2 pr = ep[e0 + k];
    int src = __float_as_int(pr.x);
    float xv = x[src * NI1 + i];
    a0 += xv; a1 = fmaf(pr.y, xv, a1);
  }
  S0[(Bd + deg) * NI1 + i] = f2b(a0); S1[(Bd + deg) * NI1 + i] = f2b(a1);
  for (int k = 0; k <= deg; ++k) {
    R0[(Bd + k) * NI1 + i] = f2b(a0 - b2f(S0[(Bd + k) * NI1 + i]));
    R1[(Bd + k) * NI1 + i] = f2b(a1 - b2f(S1[(Bd + k) * NI1 + i]));
  }
}

// ---------- rootx1 = x @ Wr1 ----------
__global__ void k_rootx1(const float* __restrict__ x, const float* __restrict__ Wr1,
                         float* __restrict__ ws) {
  int n = blockIdx.x, o = threadIdx.x;
  float s1 = 0.f;
  for (int i = 0; i < NI1; ++i) s1 = fmaf(x[n * NI1 + i], Wr1[i * HH + o], s1);
  ws[F_ROOTX1 + n * HH + o] = s1;
}

// ---------- conv1 main: per j, V = u*pick1 + v*pick0 ; agg += V @ W1b_row ----------
__global__ __launch_bounds__(512, 1)
void k_conv1(const float* __restrict__ W1a, const float* __restrict__ b1a,
             const float* __restrict__ W1b, const float* __restrict__ b1b,
             float* __restrict__ ws) {
  __shared__ ushort A_lds[128 * 168];  // V in bf16, row=d stride 168, cols k 0..159 (pad zero)
  __shared__ float a_srt[EE];
  __shared__ int off_s[NN + 1];
  int tid = threadIdx.x, bid = blockIdx.x;
  const float2* ep = (const float2*)(ws + F_EPACK);
  const int* off_g = (const int*)(ws + F_OFFG);
  for (int idx = tid; idx < EE; idx += 512) a_srt[idx] = ep[idx].y;
  if (tid <= NN) off_s[tid] = off_g[tid];
  // zero pad cols 130..167
  for (int idx = tid; idx < 128 * 38; idx += 512) {
    int d = idx / 38, c = idx - d * 38;
    A_lds[d * 168 + 130 + c] = 0;
  }
  float amin = ws[F_MM], amax = ws[F_MM + 1];
  const ushort* S0u = (const ushort*)(ws + F_S0); const ushort* S1u = (const ushort*)(ws + F_S1);
  const ushort* R0u = (const ushort*)(ws + F_R0); const ushort* R1u = (const ushort*)(ws + F_R1);
  int lane = tid & 63, wv = tid >> 6;
  int Mg = wv & 1, Ng = wv >> 1;
  int g = lane >> 4, ln = lane & 15;
  int dV = tid >> 2, qV = tid & 3;
  f32x4 acc[4];
#pragma unroll
  for (int mm = 0; mm < 4; ++mm) acc[mm] = (f32x4){0.f, 0.f, 0.f, 0.f};

  int j0 = (bid * (DH + 1)) >> 8;
  int j1 = ((bid + 1) * (DH + 1)) >> 8;
  for (int j = j0; j < j1; ++j) {
    bool pseudo = (j == DH);
    float u = pseudo ? 0.f : W1a[j];
    float v = pseudo ? 1.f : b1a[j];
    if (!pseudo && fmaxf(fmaf(u, amin, v), fmaf(u, amax, v)) <= 0.f) continue;
    const float* Brow = pseudo ? b1b : (W1b + (size_t)j * DH);
    __syncthreads();  // A_lds free (previous GEMM done)
    // --- search + V build (each thread redoes its d's search; 4 threads/d) ---
    {
      int off0 = off_s[dV], deg = off_s[dV + 1] - off0;
      bool upos = pseudo || (u > 0.f);
      int lo = 0, hi = deg;
      while (lo < hi) {
        int mid = (lo + hi) >> 1;
        float hm = fmaf(u, a_srt[off0 + mid], v);
        bool p = upos ? (hm > 0.f) : (hm <= 0.f);
        if (p) hi = mid; else lo = mid + 1;
      }
      size_t base = (size_t)(off0 + dV + lo) * NI1;
      const ushort* p0 = (upos ? R0u : S0u) + base;
      const ushort* p1 = (upos ? R1u : S1u) + base;
      ushort* arow = &A_lds[dV * 168];
#pragma unroll
      for (int c = 0; c < 16; ++c) {
        int i0 = (qV + 4 * c) * 2;
        ushort2 w0 = *(const ushort2*)(p0 + i0);
        ushort2 w1 = *(const ushort2*)(p1 + i0);
        float f0 = fmaf(u, b2f(w1.x), v * b2f(w0.x));
        float f1 = fmaf(u, b2f(w1.y), v * b2f(w0.y));
        ushort2 r; r.x = f2b(f0); r.y = f2b(f1);
        *(ushort2*)(arow + i0) = r;
      }
      if (qV == 0) {
        int i0 = 128;
        ushort2 w0 = *(const ushort2*)(p0 + i0);
        ushort2 w1 = *(const ushort2*)(p1 + i0);
        float f0 = fmaf(u, b2f(w1.x), v * b2f(w0.x));
        float f1 = fmaf(u, b2f(w1.y), v * b2f(w0.y));
        ushort2 r; r.x = f2b(f0); r.y = f2b(f1);
        *(ushort2*)(arow + i0) = r;
      }
    }
    __syncthreads();
    // --- GEMM: acc += V(128x160) @ Brow(160x64), B-frags direct from global ---
    const float* bp0 = Brow + Ng * 16 + ln;
#pragma unroll
    for (int ks = 0; ks < 5; ++ks) {
      int kb = ks * 32 + g * 8;
      float bv[8];
      if (ks < 4) {
#pragma unroll
        for (int e = 0; e < 8; ++e) bv[e] = bp0[(size_t)(kb + e) * HH];
      } else {
#pragma unroll
        for (int e = 0; e < 8; ++e) {
          int kk = kb + e;
          bv[e] = (kk < NI1) ? bp0[(size_t)kk * HH] : 0.f;
        }
      }
      short8v b8;
#pragma unroll
      for (int e = 0; e < 8; ++e) b8[e] = (short)f2b(bv[e]);
#pragma unroll
      for (int mm = 0; mm < 4; ++mm) {
        int row = (Mg * 4 + mm) * 16 + ln;
        short8v a8 = *(const short8v*)&A_lds[row * 168 + kb];
        acc[mm] = __builtin_amdgcn_mfma_f32_16x16x32_bf16(a8, b8, acc[mm], 0, 0, 0);
      }
    }
  }
  // epilogue: private slab, plain stores
  float* slab = ws + F_SLAB1 + (size_t)bid * 8192;
#pragma unroll
  for (int mm = 0; mm < 4; ++mm)
#pragma unroll
    for (int r = 0; r < 4; ++r) {
      int row = (Mg * 4 + mm) * 16 + g * 4 + r;
      int col = Ng * 16 + ln;
      slab[row * HH + col] = acc[mm][r];
    }
}

// ---------- reduce slabs + combine1 -> h1 ----------
__global__ void k_redc1(const float* __restrict__ bc1, float* __restrict__ ws) {
  int d = blockIdx.x, o = threadIdx.x;
  const int* off = (const int*)(ws + F_OFFG);
  float s = 0.f;
  for (int sl = 0; sl < 256; ++sl) s += ws[F_SLAB1 + (size_t)sl * 8192 + d * HH + o];
  int deg = off[d + 1] - off[d];
  float c = (float)(deg > 0 ? deg : 1);
  float val = s / c + ws[F_ROOTX1 + d * HH + o] + bc1[o];
  ws[F_H1 + d * HH + o] = fmaxf(val, 0.f);
}

// ---------- prep2: prefix/suffix sums of h1[src,i], a*h1[src,i] ----------
__global__ void k_prep2(float* __restrict__ ws) {
  int d = blockIdx.x, i = threadIdx.x;  // 64 threads
  const int* off = (const int*)(ws + F_OFFG);
  const float2* ep = (const float2*)(ws + F_EPACK);
  ushort* T0 = (ushort*)(ws + F_T0); ushort* T1 = (ushort*)(ws + F_T1);
  ushort* U0 = (ushort*)(ws + F_U0); ushort* U1 = (ushort*)(ws + F_U1);
  const float* h1 = ws + F_H1;
  int e0 = off[d], deg = off[d + 1] - e0;
  size_t Bd = (size_t)(e0 + d);
  float a0 = 0.f, a1 = 0.f;
  for (int k = 0; k < deg; ++k) {
    T0[(Bd + k) * HH + i] = f2b(a0); T1[(Bd + k) * HH + i] = f2b(a1);
    float2 pr = ep[e0 + k];
    int src = __float_as_int(pr.x);
    float hv = h1[src * HH + i];
    a0 += hv; a1 = fmaf(pr.y, hv, a1);
  }
  T0[(Bd + deg) * HH + i] = f2b(a0); T1[(Bd + deg) * HH + i] = f2b(a1);
  for (int k = 0; k <= deg; ++k) {
    U0[(Bd + k) * HH + i] = f2b(a0 - b2f(T0[(Bd + k) * HH + i]));
    U1[(Bd + k) * HH + i] = f2b(a1 - b2f(T1[(Bd + k) * HH + i]));
  }
}

// ---------- conv2 main (65 blocks: j=0..63 + bias pseudo-row) ----------
__global__ __launch_bounds__(512, 1)
void k_conv2(const float* __restrict__ W2a, const float* __restrict__ b2a,
             const float* __restrict__ W2b, const float* __restrict__ b2b,
             float* __restrict__ ws) {
  __shared__ ushort A_lds[128 * 72];
  __shared__ float a_srt[EE];
  __shared__ int off_s[NN + 1];
  int tid = threadIdx.x, j = blockIdx.x;
  const float2* ep = (const float2*)(ws + F_EPACK);
  const int* off_g = (const int*)(ws + F_OFFG);
  for (int idx = tid; idx < EE; idx += 512) a_srt[idx] = ep[idx].y;
  if (tid <= NN) off_s[tid] = off_g[tid];
  const ushort* T0u = (const ushort*)(ws + F_T0); const ushort* T1u = (const ushort*)(ws + F_T1);
  const ushort* U0u = (const ushort*)(ws + F_U0); const ushort* U1u = (const ushort*)(ws + F_U1);
  bool pseudo = (j == HH);
  float u = pseudo ? 0.f : W2a[j];
  float v = pseudo ? 1.f : b2a[j];
  const float* Brow = pseudo ? b2b : (W2b + (size_t)j * (HH * HH));
  int lane = tid & 63, wv = tid >> 6;
  int Mg = wv & 1, Ng = wv >> 1;
  int g = lane >> 4, ln = lane & 15;
  int dV = tid >> 2, qV = tid & 3;
  __syncthreads();
  // search + V build
  {
    int off0 = off_s[dV], deg = off_s[dV + 1] - off0;
    bool upos = pseudo || (u > 0.f);
    int lo = 0, hi = deg;
    while (lo < hi) {
      int mid = (lo + hi) >> 1;
      float hm = fmaf(u, a_srt[off0 + mid], v);
      bool p = upos ? (hm > 0.f) : (hm <= 0.f);
      if (p) hi = mid; else lo = mid + 1;
    }
    size_t base = (size_t)(off0 + dV + lo) * HH;
    const ushort* p0 = (upos ? U0u : T0u) + base;
    const ushort* p1 = (upos ? U1u : T1u) + base;
    ushort* arow = &A_lds[dV * 72];
#pragma unroll
    for (int c = 0; c < 8; ++c) {
      int i0 = (qV + 4 * c) * 2;
      ushort2 w0 = *(const ushort2*)(p0 + i0);
      ushort2 w1 = *(const ushort2*)(p1 + i0);
      float f0 = fmaf(u, b2f(w1.x), v * b2f(w0.x));
      float f1 = fmaf(u, b2f(w1.y), v * b2f(w0.y));
      ushort2 r; r.x = f2b(f0); r.y = f2b(f1);
      *(ushort2*)(arow + i0) = r;
    }
  }
  __syncthreads();
  f32x4 acc[4];
#pragma unroll
  for (int mm = 0; mm < 4; ++mm) acc[mm] = (f32x4){0.f, 0.f, 0.f, 0.f};
  const float* bp0 = Brow + Ng * 16 + ln;
#pragma unroll
  for (int ks = 0; ks < 2; ++ks) {
    int kb = ks * 32 + g * 8;
    short8v b8;
#pragma unroll
    for (int e = 0; e < 8; ++e) b8[e] = (short)f2b(bp0[(size_t)(kb + e) * HH]);
#pragma unroll
    for (int mm = 0; mm < 4; ++mm) {
      int row = (Mg * 4 + mm) * 16 + ln;
      short8v a8 = *(const short8v*)&A_lds[row * 72 + kb];
      acc[mm] = __builtin_amdgcn_mfma_f32_16x16x32_bf16(a8, b8, acc[mm], 0, 0, 0);
    }
  }
  float* slab = ws + F_SLAB2 + (size_t)j * 8192;
#pragma unroll
  for (int mm = 0; mm < 4; ++mm)
#pragma unroll
    for (int r = 0; r < 4; ++r) {
      int row = (Mg * 4 + mm) * 16 + g * 4 + r;
      int col = Ng * 16 + ln;
      slab[row * HH + col] = acc[mm][r];
    }
}

// ---------- reduce + combine2 -> h2 (rootx2 fused) ----------
__global__ void k_comb2(const float* __restrict__ Wr2, const float* __restrict__ bc2,
                        float* __restrict__ ws) {
  int d = blockIdx.x, o = threadIdx.x;
  const int* off = (const int*)(ws + F_OFFG);
  float s = 0.f;
  for (int sl = 0; sl < 65; ++sl) s += ws[F_SLAB2 + (size_t)sl * 8192 + d * HH + o];
  float rx = 0.f;
  for (int i = 0; i < HH; ++i) rx = fmaf(ws[F_H1 + d * HH + i], Wr2[i * HH + o], rx);
  int deg = off[d + 1] - off[d];
  float c = (float)(deg > 0 ? deg : 1);
  float val = s / c + rx + bc2[o];
  ws[F_H2 + d * HH + o] = fmaxf(val, 0.f);
}

// ---------- output: logits, masked softmax, packet rules ----------
__global__ void k_out(const float* __restrict__ Wout, const float* __restrict__ bout,
                      const int* __restrict__ adj, const float* __restrict__ npk,
                      const float* __restrict__ ws, float* __restrict__ out) {
  __shared__ float h2row[HH];
  __shared__ float red[128];
  int d = blockIdx.x, m = threadIdx.x;
  if (m < HH) h2row[m] = ws[F_H2 + d * HH + m];
  __syncthreads();
  float lg = bout[m];
  for (int oo = 0; oo < HH; ++oo) lg = fmaf(h2row[oo], Wout[oo * NN + m], lg);
  bool on = adj[d * NN + m] != 0;
  red[m] = on ? lg : -1e30f;
  __syncthreads();
  for (int s2 = 64; s2 > 0; s2 >>= 1) { if (m < s2) red[m] = fmaxf(red[m], red[m + s2]); __syncthreads(); }
  float mx = red[0];
  __syncthreads();
  float p = on ? expf(lg - mx) : 0.f;
  red[m] = p;
  __syncthreads();
  for (int s2 = 64; s2 > 0; s2 >>= 1) { if (m < s2) red[m] += red[m + s2]; __syncthreads(); }
  float prob = p / red[0];
  float np = npk[d];
  out[d * NN + m] = (np == -1.0f) ? ((m == d) ? 1.f : 0.f) : prob;
}

extern "C" void kernel_launch(void* const* d_in, const int* in_sizes, int n_in,
                              void* d_out, int out_size, void* d_ws, size_t ws_size,
                              hipStream_t stream) {
  const float* x   = (const float*)d_in[0];
  const int*   ei  = (const int*)d_in[1];
  const float* ea  = (const float*)d_in[2];
  const int*   adj = (const int*)d_in[3];
  const float* npk = (const float*)d_in[4];
  const float* W1a = (const float*)d_in[5];
  const float* b1a = (const float*)d_in[6];
  const float* W1b = (const float*)d_in[7];
  const float* b1b = (const float*)d_in[8];
  const float* Wr1 = (const float*)d_in[9];
  const float* bc1 = (const float*)d_in[10];
  const float* W2a = (const float*)d_in[11];
  const float* b2a = (const float*)d_in[12];
  const float* W2b = (const float*)d_in[13];
  const float* b2b = (const float*)d_in[14];
  const float* Wr2 = (const float*)d_in[15];
  const float* bc2 = (const float*)d_in[16];
  const float* Wout = (const float*)d_in[17];
  const float* bout = (const float*)d_in[18];
  float* ws = (float*)d_ws;
  float* out = (float*)d_out;

  k_prep0<<<1, 256, 0, stream>>>(ei, ea, ws);
  k_prep1<<<NN, 256, 0, stream>>>(x, ws);
  k_rootx1<<<NN, HH, 0, stream>>>(x, Wr1, ws);
  k_conv1<<<256, 512, 0, stream>>>(W1a, b1a, W1b, b1b, ws);
  k_redc1<<<NN, HH, 0, stream>>>(bc1, ws);
  k_prep2<<<NN, HH, 0, stream>>>(ws);
  k_conv2<<<65, 512, 0, stream>>>(W2a, b2a, W2b, b2b, ws);
  k_comb2<<<NN, HH, 0, stream>>>(Wr2, bc2, ws);
  k_out<<<NN, 128, 0, stream>>>(Wout, bout, adj, npk, ws, out);
}